// Round 10
// baseline (151.952 us; speedup 1.0000x reference)
//
#include <hip/hip_runtime.h>
#include <hip/hip_bf16.h>
#include <math.h>

// B=8, N=32, S=512, H=768, K=3, C=128, L=64, W=16
#define NEG_INF (-1e30f)

typedef _Float16 half8 __attribute__((ext_vector_type(8)));
typedef _Float16 half4 __attribute__((ext_vector_type(4)));
typedef float f32x4 __attribute__((ext_vector_type(4)));
typedef float f32x16 __attribute__((ext_vector_type(16)));

__device__ __forceinline__ void load_lds16(const void* g, void* l) {
  __builtin_amdgcn_global_load_lds((const __attribute__((address_space(1))) void*)g,
                                   (__attribute__((address_space(3))) void*)l, 16, 0, 0);
}

// ---------------------------------------------------------------------------
// Kernel 1 (prep): 2-plane split (K=1536):
//   A2 [4096 x 1536] f16 = [A_hi | A_lo*2^6]
//   Bt [1152 x 1536] f16 (j-major) = [B_hi | B_lo*2^6]
//   fcT[i][c] fp32
// ---------------------------------------------------------------------------
__global__ __launch_bounds__(256) void prep(
    const float* __restrict__ tokens, const float* __restrict__ span_w,
    const float* __restrict__ prefix_w, const float* __restrict__ suffix_w,
    const float* __restrict__ fc_w, _Float16* __restrict__ A2,
    _Float16* __restrict__ Bt, float* __restrict__ fcT) {
  int bid = blockIdx.x;
  int t = threadIdx.x;
  if (bid < 3072) {  // A2
    int g4 = (bid * 256 + t) * 4;
    int m = g4 / 768, h = g4 % 768;
    float4 x = *(const float4*)(tokens + g4);
    float xs[4] = {x.x, x.y, x.z, x.w};
    half4 hi, lo;
#pragma unroll
    for (int i = 0; i < 4; ++i) {
      _Float16 h_ = (_Float16)xs[i];
      hi[i] = h_;
      lo[i] = (_Float16)((xs[i] - (float)h_) * 64.0f);
    }
    size_t base = (size_t)m * 1536 + h;
    *(half4*)(A2 + base) = hi;
    *(half4*)(A2 + base + 768) = lo;
  } else if (bid < 3216) {  // Bt
    int g = (bid - 3072) * 256 + t;  // over 3*128*96 = 36864
    int ws = g / 12288;
    int r = g % 12288;
    int c = r / 96, h = (r % 96) * 8;
    const float* wsrc = (ws == 0) ? prefix_w : (ws == 1) ? span_w : suffix_w;
    const float* src = wsrc + (size_t)(c * 768 + h) * 3;
    float wv[24];
#pragma unroll
    for (int i = 0; i < 6; ++i) *(float4*)&wv[i * 4] = *(const float4*)(src + i * 4);
#pragma unroll
    for (int tap = 0; tap < 3; ++tap) {
      half8 hi, lo;
#pragma unroll
      for (int i = 0; i < 8; ++i) {
        float x = wv[i * 3 + tap];
        _Float16 h_ = (_Float16)x;
        hi[i] = h_;
        lo[i] = (_Float16)((x - (float)h_) * 64.0f);
      }
      size_t jb = (size_t)(ws * 384 + tap * 128 + c) * 1536 + h;
      *(half8*)(Bt + jb) = hi;
      *(half8*)(Bt + jb + 768) = lo;
    }
  } else {  // fcT
    int g = (bid - 3216) * 256 + t;
    int i = g >> 6, c = g & 63;
    fcT[g] = fc_w[c * 384 + i];
  }
}

// ---------------------------------------------------------------------------
// Kernel 2: MFMA GEMM (32x32x16), 64x64 WAVE-TILE for LDS-traffic reduction.
//   Ct[j][m] = aa + 2^-6*ab; per k16: aa += A0*B0; ab += A1*B0 + A0*B1.
//   M=4096, N=1152, Kplane=768. BM=128, BN=128, BK=32/plane, 256 thr
//   (4 waves, 2x2 of 64x64 tiles; each wave-tile = 2x2 mfma positions,
//   128 acc VGPR). Grid (32,9)=288. LDS 64 KB dbuf -> 2 blocks/CU.
//   Per iter/wave: 16 ds_read_b128 -> 24 MFMA (48 FLOP/LDS-byte, 2x r9).
//   r9-verified layout: row = 64 halfs = [p0 k0..31 | p1 k0..31], 16B chunks
//   XOR-swizzled by row&7; glds staging; dbuf; 1 barrier/iter.
// ---------------------------------------------------------------------------
__global__ __launch_bounds__(256) void gemm_f16(const _Float16* __restrict__ A2,
                                                const _Float16* __restrict__ Bt,
                                                float* __restrict__ Ct) {
  __shared__ _Float16 As[2][128 * 64];  // 2 x 16 KB
  __shared__ _Float16 Bs[2][128 * 64];  // 2 x 16 KB
  const int bm = blockIdx.x * 128;
  const int bj = blockIdx.y * 128;
  const int tid = threadIdx.x;
  const int w = tid >> 6;
  const int lane = tid & 63;
  // staging: 1024 chunks per array, 4 passes of 256; pass p covers rows
  // p*32 + (tid>>3), phys chunk tid&7. row&7 independent of p.
  const int srow = tid >> 3;        // 0..31 (+32p)
  const int phys = tid & 7;
  const int clog = phys ^ (srow & 7);
  const int srcoff = (clog >> 2) * 768 + (clog & 3) * 8;  // plane + k-sub
  const _Float16* gA = A2 + (size_t)(bm + srow) * 1536 + srcoff;
  const _Float16* gB = Bt + (size_t)(bj + srow) * 1536 + srcoff;
  const size_t rstep = (size_t)32 * 1536;  // +32 rows per pass
  // compute indices
  const int l31 = lane & 31;
  const int hi32 = lane >> 5;
  const int sw = lane & 7;
  const int m0w = (w & 1) * 64;
  const int n0w = (w >> 1) * 64;
#define CO(p, ks) ((((p) * 4 + (ks) * 2 + hi32) ^ sw) * 8)
  f32x16 aa[2][2], ab[2][2];
#pragma unroll
  for (int i = 0; i < 2; ++i)
#pragma unroll
    for (int j = 0; j < 2; ++j)
#pragma unroll
      for (int q = 0; q < 16; ++q) {
        aa[i][j][q] = 0.f;
        ab[i][j][q] = 0.f;
      }

  // prologue: stage iter 0 into buf 0 (4 passes A + 4 passes B)
#pragma unroll
  for (int p = 0; p < 4; ++p) {
    load_lds16(gA + (size_t)p * rstep, &As[0][p * 2048 + w * 512]);
    load_lds16(gB + (size_t)p * rstep, &Bs[0][p * 2048 + w * 512]);
  }

  for (int i = 0; i < 24; ++i) {
    const int cur = i & 1;
    __syncthreads();  // buf cur staged; prev iter's reads done
    if (i + 1 < 24) {
      const int kp = (i + 1) * 32;
      const int nxt = cur ^ 1;
#pragma unroll
      for (int p = 0; p < 4; ++p) {
        load_lds16(gA + kp + (size_t)p * rstep, &As[nxt][p * 2048 + w * 512]);
        load_lds16(gB + kp + (size_t)p * rstep, &Bs[nxt][p * 2048 + w * 512]);
      }
    }
#pragma unroll
    for (int ks = 0; ks < 2; ++ks) {
      half8 a0[2], a1[2], b0[2], b1[2];
#pragma unroll
      for (int mp = 0; mp < 2; ++mp) {
        const int row = (m0w + mp * 32 + l31) * 64;
        a0[mp] = *(const half8*)&As[cur][row + CO(0, ks)];
        a1[mp] = *(const half8*)&As[cur][row + CO(1, ks)];
      }
#pragma unroll
      for (int np = 0; np < 2; ++np) {
        const int row = (n0w + np * 32 + l31) * 64;
        b0[np] = *(const half8*)&Bs[cur][row + CO(0, ks)];
        b1[np] = *(const half8*)&Bs[cur][row + CO(1, ks)];
      }
#pragma unroll
      for (int mp = 0; mp < 2; ++mp)
#pragma unroll
        for (int np = 0; np < 2; ++np) {
          aa[mp][np] = __builtin_amdgcn_mfma_f32_32x32x16_f16(a0[mp], b0[np], aa[mp][np], 0, 0, 0);
          ab[mp][np] = __builtin_amdgcn_mfma_f32_32x32x16_f16(a1[mp], b0[np], ab[mp][np], 0, 0, 0);
          ab[mp][np] = __builtin_amdgcn_mfma_f32_32x32x16_f16(a0[mp], b1[np], ab[mp][np], 0, 0, 0);
        }
    }
  }
#undef CO
  // C/D layout (m74/m101): col(n)=lane&31, row(m)=(reg&3)+8*(reg>>2)+4*(lane>>5)
#pragma unroll
  for (int mp = 0; mp < 2; ++mp)
#pragma unroll
    for (int np = 0; np < 2; ++np) {
      const int n_out = bj + n0w + np * 32 + l31;
      float* cp = Ct + (size_t)n_out * 4096 + bm + m0w + mp * 32 + 4 * hi32;
#pragma unroll
      for (int r = 0; r < 4; ++r) {
        f32x4 v;
#pragma unroll
        for (int q = 0; q < 4; ++q)
          v[q] = aa[mp][np][4 * r + q] + 0.015625f * ab[mp][np][4 * r + q];
        *(f32x4*)(cp + 8 * r) = v;
      }
    }
}

// ---------------------------------------------------------------------------
// Kernel 3: per-(b,c) tap-combine + prefix-max / suffix-max scans
// ---------------------------------------------------------------------------
__global__ __launch_bounds__(256) void scan_kernel(const float* __restrict__ Ct,
                                                   const int* __restrict__ wsl,
                                                   float* __restrict__ PM2,
                                                   float* __restrict__ SM2) {
  int pair = blockIdx.x * 4 + (threadIdx.x >> 6);
  int b = pair >> 7;
  int c = pair & 127;
  int lane = threadIdx.x & 63;
  int mb = b * 512;
  int t0 = lane * 8;
  const float* p0 = Ct + (size_t)(0 + c) * 4096 + mb;
  const float* p1 = Ct + (size_t)(128 + c) * 4096 + mb;
  const float* p2 = Ct + (size_t)(256 + c) * 4096 + mb;
  float v[8];
#pragma unroll
  for (int i = 0; i < 8; i++) {
    int t = t0 + i;
    v[i] = (t < 494) ? (p0[t] + p1[t + 1] + p2[t + 2]) : NEG_INF;
  }
#pragma unroll
  for (int i = 1; i < 8; i++) v[i] = fmaxf(v[i], v[i - 1]);
  float x = v[7];
#pragma unroll
  for (int d = 1; d < 64; d <<= 1) {
    float y = __shfl_up(x, d);
    if (lane >= d) x = fmaxf(x, y);
  }
  float excl = __shfl_up(x, 1);
  if (lane == 0) excl = NEG_INF;
  float* pm = PM2 + (size_t)pair * 512;
#pragma unroll
  for (int i = 0; i < 8; i++) {
    int t = t0 + i;
    if (t < 494) pm[t] = fmaxf(v[i], excl);
  }
  const float* s0 = Ct + (size_t)(768 + c) * 4096 + mb;
  const float* s1 = Ct + (size_t)(896 + c) * 4096 + mb;
  const float* s2 = Ct + (size_t)(1024 + c) * 4096 + mb;
  int qmax = wsl[b] - 3;
  if (qmax > 509) qmax = 509;
  float u[8];
#pragma unroll
  for (int i = 0; i < 8; i++) {
    int q = t0 + i;
    u[i] = (q <= qmax) ? (s0[q] + s1[q + 1] + s2[q + 2]) : NEG_INF;
  }
#pragma unroll
  for (int i = 6; i >= 0; i--) u[i] = fmaxf(u[i], u[i + 1]);
  float xr = u[0];
#pragma unroll
  for (int d = 1; d < 64; d <<= 1) {
    float y = __shfl_down(xr, d);
    if (lane < 64 - d) xr = fmaxf(xr, y);
  }
  float exclr = __shfl_down(xr, 1);
  if (lane == 63) exclr = NEG_INF;
  float* sm = SM2 + (size_t)pair * 512;
#pragma unroll
  for (int i = 0; i < 8; i++) sm[t0 + i] = fmaxf(u[i], exclr);
}

// ---------------------------------------------------------------------------
// Kernel 4: per-span features + coalesced FC + sigmoid + threshold
// ---------------------------------------------------------------------------
__global__ __launch_bounds__(128) void span_kernel(
    const float* __restrict__ Ct, const float* __restrict__ PM2,
    const float* __restrict__ SM2, const float* __restrict__ prefix_b,
    const float* __restrict__ span_b, const float* __restrict__ suffix_b,
    const float* __restrict__ fcT, const float* __restrict__ fc_b,
    const int* __restrict__ spans, const int* __restrict__ wsl,
    float* __restrict__ out) {
  __shared__ float sfeat[384];
  __shared__ float part[64];
  int sp = blockIdx.x;
  int b = sp >> 5;
  int c = threadIdx.x;
  int s = spans[sp * 2], e = spans[sp * 2 + 1];
  int Lb = wsl[b];
  int mb = b * 512;
  {  // prefix (T=496)
    const float* t0p = Ct + (size_t)c * 4096 + mb;
    const float* t1p = Ct + (size_t)(128 + c) * 4096 + mb;
    float m = NEG_INF;
    if (s >= 3) m = fmaxf(m, PM2[(size_t)(b * 128 + c) * 512 + s - 3]);
    if (s >= 2 && s <= 495) m = fmaxf(m, t0p[s - 2] + t1p[s - 1]);
    if (s >= 1 && s <= 494) m = fmaxf(m, t0p[s - 1]);
    if (s <= 493) m = fmaxf(m, 0.0f);
    sfeat[c] = m + prefix_b[c];
  }
  {  // span (T=16)
    const float* u0 = Ct + (size_t)(384 + c) * 4096 + mb;
    const float* u1 = Ct + (size_t)(512 + c) * 4096 + mb;
    const float* u2 = Ct + (size_t)(640 + c) * 4096 + mb;
    int w = e - s;
    float m = NEG_INF;
    for (int p = 0; p + 2 < w; ++p)
      m = fmaxf(m, u0[s + p] + u1[s + p + 1] + u2[s + p + 2]);
    if (w >= 2 && w <= 15) m = fmaxf(m, u0[s + w - 2] + u1[s + w - 1]);
    if (w <= 14) m = fmaxf(m, u0[s + w - 1]);
    if (w <= 13) m = fmaxf(m, 0.0f);
    sfeat[128 + c] = m + span_b[c];
  }
  {  // suffix (T=511)
    const float* x0 = Ct + (size_t)(768 + c) * 4096 + mb;
    const float* x1 = Ct + (size_t)(896 + c) * 4096 + mb;
    float m = NEG_INF;
    if (e <= Lb - 3) m = fmaxf(m, SM2[(size_t)(b * 128 + c) * 512 + e]);
    if (Lb - 2 - e >= 0 && Lb - 2 - e <= 508)
      m = fmaxf(m, x0[Lb - 2] + x1[Lb - 1]);
    if (Lb - 1 - e >= 0 && Lb - 1 - e <= 508) m = fmaxf(m, x0[Lb - 1]);
    if (Lb - e <= 508) m = fmaxf(m, 0.0f);
    sfeat[256 + c] = m + suffix_b[c];
  }
  __syncthreads();
  {
    int cc = threadIdx.x & 63;
    int half = threadIdx.x >> 6;
    float acc2 = 0.0f;
    const float* fp = fcT + (size_t)(half * 192) * 64 + cc;
    const float* sf = sfeat + half * 192;
#pragma unroll 8
    for (int i = 0; i < 192; ++i) acc2 = fmaf(sf[i], fp[(size_t)i * 64], acc2);
    if (half) part[cc] = acc2;
    __syncthreads();
    if (!half) {
      float a = acc2 + part[cc] + fc_b[cc];
      float pr = 1.0f / (1.0f + expf(-a));
      out[sp * 64 + cc] = pr;
      out[16384 + sp * 64 + cc] = (pr > 0.5f) ? 1.0f : 0.0f;
    }
  }
}

// ---------------------------------------------------------------------------
extern "C" void kernel_launch(void* const* d_in, const int* in_sizes, int n_in,
                              void* d_out, int out_size, void* d_ws,
                              size_t ws_size, hipStream_t stream) {
  const float* tokens = (const float*)d_in[0];
  const float* span_w = (const float*)d_in[1];
  const float* span_b = (const float*)d_in[2];
  const float* prefix_w = (const float*)d_in[3];
  const float* prefix_b = (const float*)d_in[4];
  const float* suffix_w = (const float*)d_in[5];
  const float* suffix_b = (const float*)d_in[6];
  const float* fc_w = (const float*)d_in[7];
  const float* fc_b = (const float*)d_in[8];
  const int* spans = (const int*)d_in[9];
  const int* wsl = (const int*)d_in[10];
  float* out = (float*)d_out;

  char* ws = (char*)d_ws;
  float* Ct = (float*)ws;                     // 1152*4096*4 = 18874368
  _Float16* A2 = (_Float16*)(ws + 18874368);  // 4096*1536*2 = 12582912
  _Float16* Bt = (_Float16*)(ws + 31457280);  // 1152*1536*2 =  3538944
  float* PM2 = (float*)(ws + 34996224);       // 2097152
  float* SM2 = (float*)(ws + 37093376);       // 2097152
  float* fcT = (float*)(ws + 39190528);       // 98304

  hipLaunchKernelGGL(prep, dim3(3312), dim3(256), 0, stream, tokens, span_w,
                     prefix_w, suffix_w, fc_w, A2, Bt, fcT);
  hipLaunchKernelGGL(gemm_f16, dim3(32, 9), dim3(256), 0, stream, A2, Bt, Ct);
  hipLaunchKernelGGL(scan_kernel, dim3(256), dim3(256), 0, stream, Ct, wsl,
                     PM2, SM2);
  hipLaunchKernelGGL(span_kernel, dim3(256), dim3(128), 0, stream, Ct, PM2,
                     SM2, prefix_b, span_b, suffix_b, fcT, fc_b, spans, wsl,
                     out);
}